// Round 3
// baseline (220.415 us; speedup 1.0000x reference)
//
#include <hip/hip_runtime.h>
#include <hip/hip_bf16.h>

#define BATCH 16
#define NH    8
#define CH    8
#define HH    56
#define WW    56
#define POS   3136          // 56*56 = 49*64
#define QKVC  192
#define OC    64
#define SCALE 0.17677669529663687f   // 32^-0.5

typedef unsigned short ushort_t;
typedef __attribute__((ext_vector_type(8))) short bf16x8;   // 8 bf16 = 4 VGPRs
typedef __attribute__((ext_vector_type(4))) float f32x4;

__device__ __forceinline__ unsigned short f2b(float f) {
    __hip_bfloat16 h = __float2bfloat16(f);
    union { __hip_bfloat16 h; unsigned short u; } c; c.h = h; return c.u;
}
__device__ __forceinline__ unsigned int pk(float lo, float hi) {
    return (unsigned int)f2b(lo) | ((unsigned int)f2b(hi) << 16);
}
__device__ __forceinline__ float bu2f(ushort_t u) {
    union { unsigned int v; float f; } c; c.v = ((unsigned int)u) << 16; return c.f;
}
__device__ __forceinline__ float lo2f(unsigned int w) {       // low bf16 -> f32
    union { unsigned int v; float f; } c; c.v = w << 16; return c.f;
}
__device__ __forceinline__ float hi2f(unsigned int w) {       // high bf16 -> f32
    union { unsigned int v; float f; } c; c.v = w & 0xffff0000u; return c.f;
}
// async 16B global->LDS (lane-linear dest within wave)
__device__ __forceinline__ void gll16(const ushort_t* g, ushort_t* l) {
    __builtin_amdgcn_global_load_lds((const __attribute__((address_space(1))) void*)g,
                                     (__attribute__((address_space(3))) void*)l, 16, 0, 0);
}

// ---------------------------------------------------------------------------
// prep_x: x[b][c][pos] fp32 -> xT[b][pos][c] bf16 (canonical, no swizzle).
// 64c x 64p tile via LDS. grid (49, 4, 16), 256 thr.
// ---------------------------------------------------------------------------
__global__ __launch_bounds__(256) void prep_x(const float* __restrict__ x,
                                              ushort_t* __restrict__ xT) {
    __shared__ float ld[64][65];
    const int tid = threadIdx.x;
    const int p0 = blockIdx.x * 64, c0 = blockIdx.y * 64, b = blockIdx.z;
    const float* xb = x + ((size_t)b * 256 + c0) * POS + p0;
    #pragma unroll
    for (int it = 0; it < 4; ++it) {
        int idx = it * 256 + tid;
        int c = idx >> 4, pc = (idx & 15) << 2;
        float4 v = *(const float4*)(xb + (size_t)c * POS + pc);
        ld[c][pc] = v.x; ld[c][pc+1] = v.y; ld[c][pc+2] = v.z; ld[c][pc+3] = v.w;
    }
    __syncthreads();
    ushort_t* xo = xT + ((size_t)(b * POS + p0)) * 256 + c0;
    #pragma unroll
    for (int it = 0; it < 2; ++it) {
        int idx = it * 256 + tid;
        int p = idx >> 3, q = (idx & 7) * 8;
        uint4 st = { pk(ld[q][p],   ld[q+1][p]), pk(ld[q+2][p], ld[q+3][p]),
                     pk(ld[q+4][p], ld[q+5][p]), pk(ld[q+6][p], ld[q+7][p]) };
        *(uint4*)(xo + (size_t)p * 256 + q) = st;
    }
}

// ---------------------------------------------------------------------------
// prep_w: qkv_w (192x256) + proj_w (256x64) fp32 -> bf16, PLUS fused attn
// weight tensor wattn[h][ch][ka][12] = {w0..w8, db+rpb, db, 0}.
// grid(67), 256 thr. Blocks 0-63: weight conversion; 64-66: wattn build.
// ---------------------------------------------------------------------------
__global__ __launch_bounds__(256) void prep_w(const float* __restrict__ wq,
                                              const float* __restrict__ wp,
                                              const float* __restrict__ dc_b,
                                              const float* __restrict__ dc1_w,
                                              const float* __restrict__ dc1_b,
                                              const float* __restrict__ rpb,
                                              ushort_t* __restrict__ wq16,
                                              ushort_t* __restrict__ wp16,
                                              float* __restrict__ wattn) {
    int idx = blockIdx.x * 256 + threadIdx.x;   // 16384 float4 units + 768 wattn slots
    if (idx >= 16384) {
        int t = idx - 16384;                    // 0..767, need 576 = 8h * 72(ch*9+ka)
        if (t < 576) {
            int h = t / 72, r = t - h * 72;     // r = ch*9 + ka
            int ka = r % 9;
            float db = dc_b[r] + dc1_b[r];
            float* w = wattn + t * 12;          // t == (h*8+ch)*9 + ka
            #pragma unroll
            for (int j = 0; j < 9; ++j) w[j] = dc1_w[r * 9 + j];
            w[9]  = db + rpb[h * 9 + ka];       // K-branch bias (incl. rpb)
            w[10] = db;                         // V-branch bias
            w[11] = 0.f;
        }
        return;
    }
    const float* src; ushort_t* dst; int off;
    if (idx < 12288) { src = wq; dst = wq16; off = idx * 4; }
    else             { src = wp; dst = wp16; off = (idx - 12288) * 4; }
    float4 v = *(const float4*)(src + off);
    uint2 st = { pk(v.x, v.y), pk(v.z, v.w) };
    *(uint2*)(dst + off) = st;
}

// ---------------------------------------------------------------------------
// qkv: f = x @ qkv_w^T + b via bf16 MFMA, f bf16 [b][o][pos].
// Mtile=64, Ntile=96, full K=256. Staging 100% global_load_lds w/ XOR swizzle
// (rows 512B bank-aligned; chunk q stored at q^(row&7)). LDS 80KB = 2 blk/CU.
// grid (49, 2, 16), 256 thr.
// ---------------------------------------------------------------------------
__global__ __launch_bounds__(256) void qkv_mfma(const ushort_t* __restrict__ xT,
                                                const ushort_t* __restrict__ wq16,
                                                const float* __restrict__ bias,
                                                ushort_t* __restrict__ f16) {
    __shared__ __align__(16) ushort_t wa[64 * 256];
    __shared__ __align__(16) ushort_t wb[96 * 256];
    const int tid = threadIdx.x;
    const int p0 = blockIdx.x * 64, o0 = blockIdx.y * 96, b = blockIdx.z;

    const ushort_t* xb = xT + ((size_t)(b * POS + p0)) * 256;
    #pragma unroll
    for (int it = 0; it < 8; ++it) {        // A: 64 rows x 32 chunks
        int idx = it * 256 + tid;
        int p = idx >> 5, q = idx & 31, qs = q ^ (p & 7);
        gll16(xb + (size_t)p * 256 + qs * 8, &wa[idx * 8]);
    }
    #pragma unroll
    for (int it = 0; it < 12; ++it) {       // B: 96 rows x 32 chunks
        int idx = it * 256 + tid;
        int n = idx >> 5, q = idx & 31, qs = q ^ (n & 7);
        gll16(wq16 + (size_t)(o0 + n) * 256 + qs * 8, &wb[idx * 8]);
    }
    __syncthreads();

    const int lane = tid & 63;
    const int wid  = tid >> 6;
    const int m0   = wid * 16;
    const int ml   = lane & 15;
    const int kg   = lane >> 4;

    f32x4 acc[6];
    #pragma unroll
    for (int u = 0; u < 6; ++u) acc[u] = (f32x4){0.f, 0.f, 0.f, 0.f};

    #pragma unroll
    for (int ks = 0; ks < 8; ++ks) {
        const int pj = ((ks * 4 + kg) ^ (ml & 7)) * 8;   // swizzled chunk (m&7==n&7==ml&7)
        bf16x8 af = *(const bf16x8*)&wa[(m0 + ml) * 256 + pj];
        #pragma unroll
        for (int u = 0; u < 6; ++u) {
            bf16x8 bf = *(const bf16x8*)&wb[(u * 16 + ml) * 256 + pj];
            acc[u] = __builtin_amdgcn_mfma_f32_16x16x32_bf16(af, bf, acc[u], 0, 0, 0);
        }
    }

    #pragma unroll
    for (int u = 0; u < 6; ++u) {
        int o = o0 + u * 16 + ml;
        float bj = bias[o];
        uint2 st = { pk(acc[u][0] + bj, acc[u][1] + bj),
                     pk(acc[u][2] + bj, acc[u][3] + bj) };
        *(uint2*)(f16 + ((size_t)b * QKVC + o) * POS + p0 + m0 + kg * 4) = st;
    }
}

// ---------------------------------------------------------------------------
// attn v4: same structure as v3 (bit-packed k|v LDS, fused K/V conv pass,
// lane-pair ch split) but WITHOUT the min-waves occupancy clamp. R2's
// launch_bounds(448,6) capped VGPR at ~85 < the ~100 live values of the
// fused body -> scratch spills (VGPR=40, WRITE_SIZE 52MB vs 12.8MB ideal).
// Plain (448) lets the allocator keep vp[4][9] etc. in registers:
// ~100 VGPR -> 5 waves/SIMD -> 2 blk/CU, no spill.
// TBH=4, grid (14, 8, 16), 448 thr, LDS 11.1 KB.
// ---------------------------------------------------------------------------
#define TBH 4
#define HROW (TBH + 2)              // 6
#define HCOL (WW + 2)               // 58
#define HSZ  (HROW * HCOL)          // 348
__global__ __launch_bounds__(448) void attn_kernel(const ushort_t* __restrict__ f16,
                                                   const float* __restrict__ wattn,
                                                   float* __restrict__ aout) {
    __shared__ unsigned int kvbuf[CH][HROW][HCOL];   // k | (v<<16), raw bf16 bits

    const int tid = threadIdx.x;
    const int ty0 = blockIdx.x * TBH;
    const int h   = blockIdx.y;
    const int b   = blockIdx.z;
    const ushort_t* fb = f16 + ((size_t)b * QKVC + h * 24) * POS;

    // stage halo: 8ch x 6row x 58col packed words, pure bit-pack (no cvt)
    for (int idx = tid; idx < CH * HSZ; idx += 448) {
        int ch  = idx / HSZ;
        int rem = idx - ch * HSZ;
        int row = rem / HCOL;
        int col = rem - row * HCOL;
        int gy = ty0 + row - 1;
        int gx = col - 1;
        unsigned int w = 0;
        if (gy >= 0 && gy < HH && gx >= 0 && gx < WW) {
            int p = gy * WW + gx;
            unsigned int kk = fb[(8 + ch)  * POS + p];
            unsigned int vv = fb[(16 + ch) * POS + p];
            w = kk | (vv << 16);
        }
        (&kvbuf[0][0][0])[idx] = w;
    }
    __syncthreads();

    const int chg = tid & 1;            // lane-pair channel split
    const int pid = tid >> 1;           // 0..223
    const int ly  = pid / WW;           // 0..3
    const int lx  = pid - ly * WW;
    const int pos = (ty0 + ly) * WW + lx;
    const int cb  = chg * 4;

    // per-(h,ch) fused weights: uniform -> s_load quads
    const float4* wh = (const float4*)wattn + (size_t)h * 8 * 27;

    float q[4];
    #pragma unroll
    for (int c = 0; c < 4; ++c) q[c] = bu2f(fb[(cb + c) * POS + pos]) * SCALE;

    float logits[9];
    #pragma unroll
    for (int ka = 0; ka < 9; ++ka) logits[ka] = 0.f;
    float vp[4][9];

    #pragma unroll
    for (int c = 0; c < 4; ++c) {
        const int ch = cb + c;
        float nk[9], nv[9];
        #pragma unroll
        for (int dy = 0; dy < 3; ++dy)
            #pragma unroll
            for (int dx = 0; dx < 3; ++dx) {
                unsigned int w = kvbuf[ch][ly + dy][lx + dx];
                nk[dy * 3 + dx] = lo2f(w);
                nv[dy * 3 + dx] = hi2f(w);
            }
        const float qc = q[c];
        const float4* wp = wh + ch * 27;
        #pragma unroll
        for (int ka = 0; ka < 9; ++ka) {
            float4 a4 = wp[ka * 3 + 0];
            float4 b4 = wp[ka * 3 + 1];
            float4 c4 = wp[ka * 3 + 2];
            float kvs = nk[ka] + c4.y;
            kvs += nk[0]*a4.x + nk[1]*a4.y + nk[2]*a4.z + nk[3]*a4.w;
            kvs += nk[4]*b4.x + nk[5]*b4.y + nk[6]*b4.z + nk[7]*b4.w;
            kvs += nk[8]*c4.x;
            float vvs = nv[ka] + c4.z;
            vvs += nv[0]*a4.x + nv[1]*a4.y + nv[2]*a4.z + nv[3]*a4.w;
            vvs += nv[4]*b4.x + nv[5]*b4.y + nv[6]*b4.z + nv[7]*b4.w;
            vvs += nv[8]*c4.x;
            logits[ka] += qc * kvs;
            vp[c][ka] = vvs;
        }
    }

    // combine ch 0-3 / 4-7 partial logits across the lane pair
    #pragma unroll
    for (int ka = 0; ka < 9; ++ka) logits[ka] += __shfl_xor(logits[ka], 1);

    float m = logits[0];
    #pragma unroll
    for (int ka = 1; ka < 9; ++ka) m = fmaxf(m, logits[ka]);
    float att[9];
    float s = 0.f;
    #pragma unroll
    for (int ka = 0; ka < 9; ++ka) { att[ka] = __expf(logits[ka] - m); s += att[ka]; }
    float inv = 1.f / s;
    #pragma unroll
    for (int ka = 0; ka < 9; ++ka) att[ka] *= inv;

    float* ap = aout + ((size_t)b * OC + h * CH + cb) * POS + pos;
    #pragma unroll
    for (int c = 0; c < 4; ++c) {
        float o = 0.f;
        #pragma unroll
        for (int ka = 0; ka < 9; ++ka) o += att[ka] * vp[c][ka];
        ap[c * POS] = o;
    }
}
#undef TBH

// ---------------------------------------------------------------------------
// proj: out = a @ proj_w^T + b. A: coalesced fp32 -> LDS -> bf16 transpose.
// B: global_load_lds of pre-converted wp16 (swizzled). Mtile=64, Ntile=128.
// LDS ~42KB = 3 blk/CU. grid (49, 2, 16), 256 thr.
// ---------------------------------------------------------------------------
__global__ __launch_bounds__(256) void proj_mfma(const float* __restrict__ a,
                                                 const ushort_t* __restrict__ wp16,
                                                 const float* __restrict__ bias,
                                                 float* __restrict__ out) {
    __shared__ float ld[64][65];
    __shared__ __align__(16) ushort_t wa[64 * 72];
    __shared__ __align__(16) ushort_t wb[128 * 64];
    const int tid = threadIdx.x;
    const int p0 = blockIdx.x * 64, o0 = blockIdx.y * 128, b = blockIdx.z;

    // B: async GLL (rows 128B = 8 chunks, swizzled)
    #pragma unroll
    for (int it = 0; it < 4; ++it) {
        int idx = it * 256 + tid;
        int n = idx >> 3, q = idx & 7, qs = q ^ (n & 7);
        gll16(wp16 + (size_t)(o0 + n) * 64 + qs * 8, &wb[idx * 8]);
    }
    // A: coalesced fp32 tile
    const float* ab = a + (size_t)b * OC * POS + p0;
    #pragma unroll
    for (int it = 0; it < 4; ++it) {
        int idx = it * 256 + tid;
        int c = idx >> 4, pc = (idx & 15) << 2;
        float4 v = *(const float4*)(ab + (size_t)c * POS + pc);
        ld[c][pc] = v.x; ld[c][pc+1] = v.y; ld[c][pc+2] = v.z; ld[c][pc+3] = v.w;
    }
    __syncthreads();
    // pack transpose: wa[p][ch] stride 72
    #pragma unroll
    for (int it = 0; it < 2; ++it) {
        int idx = it * 256 + tid;
        int p = idx >> 3, q = (idx & 7) * 8;
        uint4 st = { pk(ld[q][p],   ld[q+1][p]), pk(ld[q+2][p], ld[q+3][p]),
                     pk(ld[q+4][p], ld[q+5][p]), pk(ld[q+6][p], ld[q+7][p]) };
        *(uint4*)&wa[p * 72 + q] = st;
    }
    __syncthreads();

    const int lane = tid & 63;
    const int wid  = tid >> 6;
    const int m0   = wid * 16;
    const int ml   = lane & 15;
    const int kg   = lane >> 4;

    f32x4 acc[8];
    #pragma unroll
    for (int u = 0; u < 8; ++u) acc[u] = (f32x4){0.f, 0.f, 0.f, 0.f};

    #pragma unroll
    for (int s = 0; s < 2; ++s) {
        bf16x8 af = *(const bf16x8*)&wa[(m0 + ml) * 72 + s * 32 + kg * 8];
        const int pj = ((s * 4 + kg) ^ (ml & 7)) * 8;
        #pragma unroll
        for (int u = 0; u < 8; ++u) {
            bf16x8 bf = *(const bf16x8*)&wb[(u * 16 + ml) * 64 + pj];
            acc[u] = __builtin_amdgcn_mfma_f32_16x16x32_bf16(af, bf, acc[u], 0, 0, 0);
        }
    }

    #pragma unroll
    for (int u = 0; u < 8; ++u) {
        int o = o0 + u * 16 + ml;
        float bj = bias[o];
        float4 st = { acc[u][0] + bj, acc[u][1] + bj, acc[u][2] + bj, acc[u][3] + bj };
        *(float4*)(out + ((size_t)b * 256 + o) * POS + p0 + m0 + kg * 4) = st;
    }
}

// ---------------------------------------------------------------------------
extern "C" void kernel_launch(void* const* d_in, const int* in_sizes, int n_in,
                              void* d_out, int out_size, void* d_ws, size_t ws_size,
                              hipStream_t stream) {
    const float* x      = (const float*)d_in[0];
    const float* qkv_w  = (const float*)d_in[1];
    const float* qkv_b  = (const float*)d_in[2];
    const float* dc_b   = (const float*)d_in[3];
    const float* dc1_w  = (const float*)d_in[4];
    const float* dc1_b  = (const float*)d_in[5];
    const float* rpb    = (const float*)d_in[6];
    const float* proj_w = (const float*)d_in[7];
    const float* proj_b = (const float*)d_in[8];
    float* out = (float*)d_out;

    // ws layout (45.1 MB base):
    //   f16   bf16 16*192*3136 = 19.27 MB
    //   xT    bf16 16*3136*256 = 25.69 MB  (dead after qkv; 'a' aliases it)
    //   wq16  96 KB, wp16 32 KB
    //   wattn 27 KB (fused attn weights) -- falls back to d_out scratch if
    //   ws is exactly-sized (d_out fully overwritten by proj afterwards).
    ushort_t* f16  = (ushort_t*)d_ws;
    ushort_t* xT   = f16 + (size_t)BATCH * QKVC * POS;
    ushort_t* wq16 = xT + (size_t)BATCH * POS * 256;
    ushort_t* wp16 = wq16 + 192 * 256;
    float*    a    = (float*)xT;            // alias: xT dead before attn writes

    const size_t WS_BASE = 45088768;        // bytes used by the four bufs above
    float* wattn = (ws_size >= WS_BASE + 6912 * sizeof(float))
                 ? (float*)((char*)d_ws + WS_BASE)
                 : (float*)d_out;           // scratch; proj rewrites all of out

    prep_x   <<<dim3(49, 4, BATCH), 256, 0, stream>>>(x, xT);
    prep_w   <<<dim3(67),           256, 0, stream>>>(qkv_w, proj_w, dc_b, dc1_w,
                                                      dc1_b, rpb, wq16, wp16, wattn);
    qkv_mfma <<<dim3(49, 2, BATCH), 256, 0, stream>>>(xT, wq16, qkv_b, f16);
    attn_kernel<<<dim3(14, NH, BATCH), 448, 0, stream>>>(f16, wattn, a);
    proj_mfma<<<dim3(49, 2, BATCH), 256, 0, stream>>>(a, wp16, proj_b, out);
}

// Round 4
// 190.719 us; speedup vs baseline: 1.1557x; 1.1557x over previous
//
#include <hip/hip_runtime.h>
#include <hip/hip_bf16.h>

#define BATCH 16
#define NH    8
#define CH    8
#define HH    56
#define WW    56
#define POS   3136          // 56*56 = 49*64
#define QKVC  192
#define OC    64
#define SCALE 0.17677669529663687f   // 32^-0.5

typedef unsigned short ushort_t;
typedef __attribute__((ext_vector_type(8))) short bf16x8;   // 8 bf16 = 4 VGPRs
typedef __attribute__((ext_vector_type(4))) float f32x4;

__device__ __forceinline__ unsigned short f2b(float f) {
    __hip_bfloat16 h = __float2bfloat16(f);
    union { __hip_bfloat16 h; unsigned short u; } c; c.h = h; return c.u;
}
__device__ __forceinline__ unsigned int pk(float lo, float hi) {
    return (unsigned int)f2b(lo) | ((unsigned int)f2b(hi) << 16);
}
__device__ __forceinline__ float bu2f(ushort_t u) {
    union { unsigned int v; float f; } c; c.v = ((unsigned int)u) << 16; return c.f;
}
__device__ __forceinline__ float lo2f(unsigned int w) {       // low bf16 -> f32
    union { unsigned int v; float f; } c; c.v = w << 16; return c.f;
}
__device__ __forceinline__ float hi2f(unsigned int w) {       // high bf16 -> f32
    union { unsigned int v; float f; } c; c.v = w & 0xffff0000u; return c.f;
}
// async 16B global->LDS (lane-linear dest within wave)
__device__ __forceinline__ void gll16(const ushort_t* g, ushort_t* l) {
    __builtin_amdgcn_global_load_lds((const __attribute__((address_space(1))) void*)g,
                                     (__attribute__((address_space(3))) void*)l, 16, 0, 0);
}

// ---------------------------------------------------------------------------
// prep_x: x[b][c][pos] fp32 -> xT[b][pos][c] bf16 (canonical, no swizzle).
// 64c x 64p tile via LDS. grid (49, 4, 16), 256 thr.
// ---------------------------------------------------------------------------
__global__ __launch_bounds__(256) void prep_x(const float* __restrict__ x,
                                              ushort_t* __restrict__ xT) {
    __shared__ float ld[64][65];
    const int tid = threadIdx.x;
    const int p0 = blockIdx.x * 64, c0 = blockIdx.y * 64, b = blockIdx.z;
    const float* xb = x + ((size_t)b * 256 + c0) * POS + p0;
    #pragma unroll
    for (int it = 0; it < 4; ++it) {
        int idx = it * 256 + tid;
        int c = idx >> 4, pc = (idx & 15) << 2;
        float4 v = *(const float4*)(xb + (size_t)c * POS + pc);
        ld[c][pc] = v.x; ld[c][pc+1] = v.y; ld[c][pc+2] = v.z; ld[c][pc+3] = v.w;
    }
    __syncthreads();
    ushort_t* xo = xT + ((size_t)(b * POS + p0)) * 256 + c0;
    #pragma unroll
    for (int it = 0; it < 2; ++it) {
        int idx = it * 256 + tid;
        int p = idx >> 3, q = (idx & 7) * 8;
        uint4 st = { pk(ld[q][p],   ld[q+1][p]), pk(ld[q+2][p], ld[q+3][p]),
                     pk(ld[q+4][p], ld[q+5][p]), pk(ld[q+6][p], ld[q+7][p]) };
        *(uint4*)(xo + (size_t)p * 256 + q) = st;
    }
}

// ---------------------------------------------------------------------------
// prep_w: qkv_w (192x256) + proj_w (256x64) fp32 -> bf16, PLUS fused attn
// weight tensor wattn[h][ch][ka][12] = {w0..w8, db+rpb, db, 0}.
// grid(67), 256 thr. Blocks 0-63: weight conversion; 64-66: wattn build.
// ---------------------------------------------------------------------------
__global__ __launch_bounds__(256) void prep_w(const float* __restrict__ wq,
                                              const float* __restrict__ wp,
                                              const float* __restrict__ dc_b,
                                              const float* __restrict__ dc1_w,
                                              const float* __restrict__ dc1_b,
                                              const float* __restrict__ rpb,
                                              ushort_t* __restrict__ wq16,
                                              ushort_t* __restrict__ wp16,
                                              float* __restrict__ wattn) {
    int idx = blockIdx.x * 256 + threadIdx.x;   // 16384 float4 units + 768 wattn slots
    if (idx >= 16384) {
        int t = idx - 16384;                    // 0..767, need 576 = 8h * 72(ch*9+ka)
        if (t < 576) {
            int h = t / 72, r = t - h * 72;     // r = ch*9 + ka
            int ka = r % 9;
            float db = dc_b[r] + dc1_b[r];
            float* w = wattn + t * 12;          // t == (h*8+ch)*9 + ka
            #pragma unroll
            for (int j = 0; j < 9; ++j) w[j] = dc1_w[r * 9 + j];
            w[9]  = db + rpb[h * 9 + ka];       // K-branch bias (incl. rpb)
            w[10] = db;                         // V-branch bias
            w[11] = 0.f;
        }
        return;
    }
    const float* src; ushort_t* dst; int off;
    if (idx < 12288) { src = wq; dst = wq16; off = idx * 4; }
    else             { src = wp; dst = wp16; off = (idx - 12288) * 4; }
    float4 v = *(const float4*)(src + off);
    uint2 st = { pk(v.x, v.y), pk(v.z, v.w) };
    *(uint2*)(dst + off) = st;
}

// ---------------------------------------------------------------------------
// qkv: f = x @ qkv_w^T + b via bf16 MFMA, f bf16 [b][o][pos].
// Mtile=64, Ntile=96, full K=256. Staging 100% global_load_lds w/ XOR swizzle
// (rows 512B bank-aligned; chunk q stored at q^(row&7)). LDS 80KB = 2 blk/CU.
// grid (49, 2, 16), 256 thr.
// ---------------------------------------------------------------------------
__global__ __launch_bounds__(256) void qkv_mfma(const ushort_t* __restrict__ xT,
                                                const ushort_t* __restrict__ wq16,
                                                const float* __restrict__ bias,
                                                ushort_t* __restrict__ f16) {
    __shared__ __align__(16) ushort_t wa[64 * 256];
    __shared__ __align__(16) ushort_t wb[96 * 256];
    const int tid = threadIdx.x;
    const int p0 = blockIdx.x * 64, o0 = blockIdx.y * 96, b = blockIdx.z;

    const ushort_t* xb = xT + ((size_t)(b * POS + p0)) * 256;
    #pragma unroll
    for (int it = 0; it < 8; ++it) {        // A: 64 rows x 32 chunks
        int idx = it * 256 + tid;
        int p = idx >> 5, q = idx & 31, qs = q ^ (p & 7);
        gll16(xb + (size_t)p * 256 + qs * 8, &wa[idx * 8]);
    }
    #pragma unroll
    for (int it = 0; it < 12; ++it) {       // B: 96 rows x 32 chunks
        int idx = it * 256 + tid;
        int n = idx >> 5, q = idx & 31, qs = q ^ (n & 7);
        gll16(wq16 + (size_t)(o0 + n) * 256 + qs * 8, &wb[idx * 8]);
    }
    __syncthreads();

    const int lane = tid & 63;
    const int wid  = tid >> 6;
    const int m0   = wid * 16;
    const int ml   = lane & 15;
    const int kg   = lane >> 4;

    f32x4 acc[6];
    #pragma unroll
    for (int u = 0; u < 6; ++u) acc[u] = (f32x4){0.f, 0.f, 0.f, 0.f};

    #pragma unroll
    for (int ks = 0; ks < 8; ++ks) {
        const int pj = ((ks * 4 + kg) ^ (ml & 7)) * 8;   // swizzled chunk (m&7==n&7==ml&7)
        bf16x8 af = *(const bf16x8*)&wa[(m0 + ml) * 256 + pj];
        #pragma unroll
        for (int u = 0; u < 6; ++u) {
            bf16x8 bf = *(const bf16x8*)&wb[(u * 16 + ml) * 256 + pj];
            acc[u] = __builtin_amdgcn_mfma_f32_16x16x32_bf16(af, bf, acc[u], 0, 0, 0);
        }
    }

    #pragma unroll
    for (int u = 0; u < 6; ++u) {
        int o = o0 + u * 16 + ml;
        float bj = bias[o];
        uint2 st = { pk(acc[u][0] + bj, acc[u][1] + bj),
                     pk(acc[u][2] + bj, acc[u][3] + bj) };
        *(uint2*)(f16 + ((size_t)b * QKVC + o) * POS + p0 + m0 + kg * 4) = st;
    }
}

// ---------------------------------------------------------------------------
// attn v5: R1's proven TWO-PASS structure (K-pass -> softmax -> V-pass;
// only att[9] lives across passes => no spill, R1 measured VGPR=56) with
// v3's bit-packed k|(v<<16) LDS buffer (bit-exact; halves staging writes
// and LDS footprint 37.4->18.6 KB). q-loads hoisted above staging so HBM
// latency hides under the stage loop. The fused single-pass (R2/R3) is
// abandoned: vp[4][9] cross-loop state forced scratch spills both times.
// TBH=8, grid (7, 8, 16), 448 thr.
// ---------------------------------------------------------------------------
#define TBH 8
#define HROW (TBH + 2)              // 10
#define HCOL (WW + 2)               // 58
#define HSZ  (HROW * HCOL)          // 580
__global__ __launch_bounds__(448) void attn_kernel(const ushort_t* __restrict__ f16,
                                                   const float* __restrict__ wattn,
                                                   float* __restrict__ aout) {
    __shared__ unsigned int kvbuf[CH][HROW][HCOL];   // k | (v<<16), raw bf16 bits

    const int tid = threadIdx.x;
    const int ty0 = blockIdx.x * TBH;
    const int h   = blockIdx.y;
    const int b   = blockIdx.z;
    const ushort_t* fb = f16 + ((size_t)b * QKVC + h * 24) * POS;

    const int ly  = tid / WW;           // 0..7
    const int lx  = tid - ly * WW;
    const int pos = (ty0 + ly) * WW + lx;

    // q loads issued BEFORE staging: latency overlaps the stage loop
    float q[CH];
    #pragma unroll
    for (int ch = 0; ch < CH; ++ch) q[ch] = bu2f(fb[ch * POS + pos]) * SCALE;

    // stage halo: 8ch x 10row x 58col packed words, pure bit-pack (no cvt)
    for (int idx = tid; idx < CH * HSZ; idx += 448) {
        int ch  = idx / HSZ;
        int rem = idx - ch * HSZ;
        int row = rem / HCOL;
        int col = rem - row * HCOL;
        int gy = ty0 + row - 1;
        int gx = col - 1;
        unsigned int w = 0;
        if (gy >= 0 && gy < HH && gx >= 0 && gx < WW) {
            int p = gy * WW + gx;
            unsigned int kk = fb[(8 + ch)  * POS + p];
            unsigned int vv = fb[(16 + ch) * POS + p];
            w = kk | (vv << 16);
        }
        (&kvbuf[0][0][0])[idx] = w;
    }
    __syncthreads();

    // per-(h,ch) fused weights: uniform -> s_load quads
    const float4* wh = (const float4*)wattn + (size_t)h * 8 * 27;

    // ---- pass 1: K-conv -> logits ----
    float logits[9];
    #pragma unroll
    for (int ka = 0; ka < 9; ++ka) logits[ka] = 0.f;
    #pragma unroll
    for (int ch = 0; ch < CH; ++ch) {
        float nk[9];
        #pragma unroll
        for (int dy = 0; dy < 3; ++dy)
            #pragma unroll
            for (int dx = 0; dx < 3; ++dx)
                nk[dy * 3 + dx] = lo2f(kvbuf[ch][ly + dy][lx + dx]);
        const float qc = q[ch];
        const float4* wp = wh + ch * 27;
        #pragma unroll
        for (int ka = 0; ka < 9; ++ka) {
            float4 a4 = wp[ka * 3 + 0];
            float4 b4 = wp[ka * 3 + 1];
            float4 c4 = wp[ka * 3 + 2];
            float kv = nk[ka] + c4.y;
            kv += nk[0]*a4.x + nk[1]*a4.y + nk[2]*a4.z + nk[3]*a4.w;
            kv += nk[4]*b4.x + nk[5]*b4.y + nk[6]*b4.z + nk[7]*b4.w;
            kv += nk[8]*c4.x;
            logits[ka] += qc * kv;
        }
    }

    // ---- softmax ----
    float m = logits[0];
    #pragma unroll
    for (int ka = 1; ka < 9; ++ka) m = fmaxf(m, logits[ka]);
    float att[9];
    float s = 0.f;
    #pragma unroll
    for (int ka = 0; ka < 9; ++ka) { att[ka] = __expf(logits[ka] - m); s += att[ka]; }
    float inv = 1.f / s;
    #pragma unroll
    for (int ka = 0; ka < 9; ++ka) att[ka] *= inv;

    // ---- pass 2: V-conv -> weighted sum, store per-ch (minimal live state) ----
    float* ap = aout + ((size_t)b * OC + h * CH) * POS + pos;
    #pragma unroll
    for (int ch = 0; ch < CH; ++ch) {
        float nv[9];
        #pragma unroll
        for (int dy = 0; dy < 3; ++dy)
            #pragma unroll
            for (int dx = 0; dx < 3; ++dx)
                nv[dy * 3 + dx] = hi2f(kvbuf[ch][ly + dy][lx + dx]);
        const float4* wp = wh + ch * 27;
        float o = 0.f;
        #pragma unroll
        for (int ka = 0; ka < 9; ++ka) {
            float4 a4 = wp[ka * 3 + 0];
            float4 b4 = wp[ka * 3 + 1];
            float4 c4 = wp[ka * 3 + 2];
            float vv = nv[ka] + c4.z;
            vv += nv[0]*a4.x + nv[1]*a4.y + nv[2]*a4.z + nv[3]*a4.w;
            vv += nv[4]*b4.x + nv[5]*b4.y + nv[6]*b4.z + nv[7]*b4.w;
            vv += nv[8]*c4.x;
            o += att[ka] * vv;
        }
        ap[ch * POS] = o;
    }
}
#undef TBH

// ---------------------------------------------------------------------------
// proj: out = a @ proj_w^T + b. A: coalesced fp32 -> LDS -> bf16 transpose.
// B: global_load_lds of pre-converted wp16 (swizzled). Mtile=64, Ntile=128.
// LDS ~42KB = 3 blk/CU. grid (49, 2, 16), 256 thr.
// ---------------------------------------------------------------------------
__global__ __launch_bounds__(256) void proj_mfma(const float* __restrict__ a,
                                                 const ushort_t* __restrict__ wp16,
                                                 const float* __restrict__ bias,
                                                 float* __restrict__ out) {
    __shared__ float ld[64][65];
    __shared__ __align__(16) ushort_t wa[64 * 72];
    __shared__ __align__(16) ushort_t wb[128 * 64];
    const int tid = threadIdx.x;
    const int p0 = blockIdx.x * 64, o0 = blockIdx.y * 128, b = blockIdx.z;

    // B: async GLL (rows 128B = 8 chunks, swizzled)
    #pragma unroll
    for (int it = 0; it < 4; ++it) {
        int idx = it * 256 + tid;
        int n = idx >> 3, q = idx & 7, qs = q ^ (n & 7);
        gll16(wp16 + (size_t)(o0 + n) * 64 + qs * 8, &wb[idx * 8]);
    }
    // A: coalesced fp32 tile
    const float* ab = a + (size_t)b * OC * POS + p0;
    #pragma unroll
    for (int it = 0; it < 4; ++it) {
        int idx = it * 256 + tid;
        int c = idx >> 4, pc = (idx & 15) << 2;
        float4 v = *(const float4*)(ab + (size_t)c * POS + pc);
        ld[c][pc] = v.x; ld[c][pc+1] = v.y; ld[c][pc+2] = v.z; ld[c][pc+3] = v.w;
    }
    __syncthreads();
    // pack transpose: wa[p][ch] stride 72
    #pragma unroll
    for (int it = 0; it < 2; ++it) {
        int idx = it * 256 + tid;
        int p = idx >> 3, q = (idx & 7) * 8;
        uint4 st = { pk(ld[q][p],   ld[q+1][p]), pk(ld[q+2][p], ld[q+3][p]),
                     pk(ld[q+4][p], ld[q+5][p]), pk(ld[q+6][p], ld[q+7][p]) };
        *(uint4*)&wa[p * 72 + q] = st;
    }
    __syncthreads();

    const int lane = tid & 63;
    const int wid  = tid >> 6;
    const int m0   = wid * 16;
    const int ml   = lane & 15;
    const int kg   = lane >> 4;

    f32x4 acc[8];
    #pragma unroll
    for (int u = 0; u < 8; ++u) acc[u] = (f32x4){0.f, 0.f, 0.f, 0.f};

    #pragma unroll
    for (int s = 0; s < 2; ++s) {
        bf16x8 af = *(const bf16x8*)&wa[(m0 + ml) * 72 + s * 32 + kg * 8];
        const int pj = ((s * 4 + kg) ^ (ml & 7)) * 8;
        #pragma unroll
        for (int u = 0; u < 8; ++u) {
            bf16x8 bf = *(const bf16x8*)&wb[(u * 16 + ml) * 64 + pj];
            acc[u] = __builtin_amdgcn_mfma_f32_16x16x32_bf16(af, bf, acc[u], 0, 0, 0);
        }
    }

    #pragma unroll
    for (int u = 0; u < 8; ++u) {
        int o = o0 + u * 16 + ml;
        float bj = bias[o];
        float4 st = { acc[u][0] + bj, acc[u][1] + bj, acc[u][2] + bj, acc[u][3] + bj };
        *(float4*)(out + ((size_t)b * 256 + o) * POS + p0 + m0 + kg * 4) = st;
    }
}

// ---------------------------------------------------------------------------
extern "C" void kernel_launch(void* const* d_in, const int* in_sizes, int n_in,
                              void* d_out, int out_size, void* d_ws, size_t ws_size,
                              hipStream_t stream) {
    const float* x      = (const float*)d_in[0];
    const float* qkv_w  = (const float*)d_in[1];
    const float* qkv_b  = (const float*)d_in[2];
    const float* dc_b   = (const float*)d_in[3];
    const float* dc1_w  = (const float*)d_in[4];
    const float* dc1_b  = (const float*)d_in[5];
    const float* rpb    = (const float*)d_in[6];
    const float* proj_w = (const float*)d_in[7];
    const float* proj_b = (const float*)d_in[8];
    float* out = (float*)d_out;

    // ws layout (45.1 MB base):
    //   f16   bf16 16*192*3136 = 19.27 MB
    //   xT    bf16 16*3136*256 = 25.69 MB  (dead after qkv; 'a' aliases it)
    //   wq16  96 KB, wp16 32 KB
    //   wattn 27 KB (fused attn weights) -- falls back to d_out scratch if
    //   ws is exactly-sized (d_out fully overwritten by proj afterwards).
    ushort_t* f16  = (ushort_t*)d_ws;
    ushort_t* xT   = f16 + (size_t)BATCH * QKVC * POS;
    ushort_t* wq16 = xT + (size_t)BATCH * POS * 256;
    ushort_t* wp16 = wq16 + 192 * 256;
    float*    a    = (float*)xT;            // alias: xT dead before attn writes

    const size_t WS_BASE = 45088768;        // bytes used by the four bufs above
    float* wattn = (ws_size >= WS_BASE + 6912 * sizeof(float))
                 ? (float*)((char*)d_ws + WS_BASE)
                 : (float*)d_out;           // scratch; proj rewrites all of out

    prep_x   <<<dim3(49, 4, BATCH), 256, 0, stream>>>(x, xT);
    prep_w   <<<dim3(67),           256, 0, stream>>>(qkv_w, proj_w, dc_b, dc1_w,
                                                      dc1_b, rpb, wq16, wp16, wattn);
    qkv_mfma <<<dim3(49, 2, BATCH), 256, 0, stream>>>(xT, wq16, qkv_b, f16);
    attn_kernel<<<dim3(7, NH, BATCH), 448, 0, stream>>>(f16, wattn, a);
    proj_mfma<<<dim3(49, 2, BATCH), 256, 0, stream>>>(a, wp16, proj_b, out);
}

// Round 5
// 184.768 us; speedup vs baseline: 1.1929x; 1.0322x over previous
//
#include <hip/hip_runtime.h>
#include <hip/hip_bf16.h>

#define BATCH 16
#define NH    8
#define CH    8
#define HH    56
#define WW    56
#define POS   3136          // 56*56 = 49*64
#define QKVC  192
#define OC    64
#define SCALE 0.17677669529663687f   // 32^-0.5

typedef unsigned short ushort_t;
typedef __attribute__((ext_vector_type(8))) short bf16x8;   // 8 bf16 = 4 VGPRs
typedef __attribute__((ext_vector_type(4))) float f32x4;

__device__ __forceinline__ unsigned short f2b(float f) {
    __hip_bfloat16 h = __float2bfloat16(f);
    union { __hip_bfloat16 h; unsigned short u; } c; c.h = h; return c.u;
}
__device__ __forceinline__ unsigned int pk(float lo, float hi) {
    return (unsigned int)f2b(lo) | ((unsigned int)f2b(hi) << 16);
}
__device__ __forceinline__ float bu2f(ushort_t u) {
    union { unsigned int v; float f; } c; c.v = ((unsigned int)u) << 16; return c.f;
}
__device__ __forceinline__ float lo2f(unsigned int w) {       // low bf16 -> f32
    union { unsigned int v; float f; } c; c.v = w << 16; return c.f;
}
__device__ __forceinline__ float hi2f(unsigned int w) {       // high bf16 -> f32
    union { unsigned int v; float f; } c; c.v = w & 0xffff0000u; return c.f;
}
// async 16B global->LDS (lane-linear dest within wave)
__device__ __forceinline__ void gll16(const ushort_t* g, ushort_t* l) {
    __builtin_amdgcn_global_load_lds((const __attribute__((address_space(1))) void*)g,
                                     (__attribute__((address_space(3))) void*)l, 16, 0, 0);
}

// ---------------------------------------------------------------------------
// prep_xw: z<16 -> x[b][c][pos] fp32 -> xT[b][pos][c] bf16 (64c x 64p tile).
//          z==16 -> weight prep (qkv_w/proj_w -> bf16, wattn build), 67 of
//          the 196 (x,y) blocks active. Merging saves one serial launch.
// grid (49, 4, 17), 256 thr.
// ---------------------------------------------------------------------------
__global__ __launch_bounds__(256) void prep_xw(const float* __restrict__ x,
                                               ushort_t* __restrict__ xT,
                                               const float* __restrict__ wq,
                                               const float* __restrict__ wp,
                                               const float* __restrict__ dc_b,
                                               const float* __restrict__ dc1_w,
                                               const float* __restrict__ dc1_b,
                                               const float* __restrict__ rpb,
                                               ushort_t* __restrict__ wq16,
                                               ushort_t* __restrict__ wp16,
                                               float* __restrict__ wattn) {
    const int tid = threadIdx.x;
    if (blockIdx.z == BATCH) {
        int bid = blockIdx.y * 49 + blockIdx.x;
        if (bid >= 67) return;
        int idx = bid * 256 + tid;              // 16384 float4 units + wattn slots
        if (idx >= 16384) {
            int t = idx - 16384;                // need 576 = 8h * 72(ch*9+ka)
            if (t < 576) {
                int h = t / 72, r = t - h * 72; // r = ch*9 + ka
                int ka = r % 9;
                float db = dc_b[r] + dc1_b[r];
                float* w = wattn + t * 12;      // t == (h*8+ch)*9 + ka
                #pragma unroll
                for (int j = 0; j < 9; ++j) w[j] = dc1_w[r * 9 + j];
                w[9]  = db + rpb[h * 9 + ka];   // K-branch bias (incl. rpb)
                w[10] = db;                     // V-branch bias
                w[11] = 0.f;
            }
            return;
        }
        const float* src; ushort_t* dst; int off;
        if (idx < 12288) { src = wq; dst = wq16; off = idx * 4; }
        else             { src = wp; dst = wp16; off = (idx - 12288) * 4; }
        float4 v = *(const float4*)(src + off);
        uint2 st = { pk(v.x, v.y), pk(v.z, v.w) };
        *(uint2*)(dst + off) = st;
        return;
    }

    __shared__ float ld[64][65];
    const int p0 = blockIdx.x * 64, c0 = blockIdx.y * 64, b = blockIdx.z;
    const float* xb = x + ((size_t)b * 256 + c0) * POS + p0;
    #pragma unroll
    for (int it = 0; it < 4; ++it) {
        int idx = it * 256 + tid;
        int c = idx >> 4, pc = (idx & 15) << 2;
        float4 v = *(const float4*)(xb + (size_t)c * POS + pc);
        ld[c][pc] = v.x; ld[c][pc+1] = v.y; ld[c][pc+2] = v.z; ld[c][pc+3] = v.w;
    }
    __syncthreads();
    ushort_t* xo = xT + ((size_t)(b * POS + p0)) * 256 + c0;
    #pragma unroll
    for (int it = 0; it < 2; ++it) {
        int idx = it * 256 + tid;
        int p = idx >> 3, q = (idx & 7) * 8;
        uint4 st = { pk(ld[q][p],   ld[q+1][p]), pk(ld[q+2][p], ld[q+3][p]),
                     pk(ld[q+4][p], ld[q+5][p]), pk(ld[q+6][p], ld[q+7][p]) };
        *(uint4*)(xo + (size_t)p * 256 + q) = st;
    }
}

// ---------------------------------------------------------------------------
// qkv: f = x @ qkv_w^T + b via bf16 MFMA, f bf16 [b][o][pos].
// Mtile=64, Ntile=96, full K=256. Staging 100% global_load_lds w/ XOR swizzle
// (rows 512B bank-aligned; chunk q stored at q^(row&7)). LDS 80KB = 2 blk/CU.
// grid (49, 2, 16), 256 thr.
// ---------------------------------------------------------------------------
__global__ __launch_bounds__(256) void qkv_mfma(const ushort_t* __restrict__ xT,
                                                const ushort_t* __restrict__ wq16,
                                                const float* __restrict__ bias,
                                                ushort_t* __restrict__ f16) {
    __shared__ __align__(16) ushort_t wa[64 * 256];
    __shared__ __align__(16) ushort_t wb[96 * 256];
    const int tid = threadIdx.x;
    const int p0 = blockIdx.x * 64, o0 = blockIdx.y * 96, b = blockIdx.z;

    const ushort_t* xb = xT + ((size_t)(b * POS + p0)) * 256;
    #pragma unroll
    for (int it = 0; it < 8; ++it) {        // A: 64 rows x 32 chunks
        int idx = it * 256 + tid;
        int p = idx >> 5, q = idx & 31, qs = q ^ (p & 7);
        gll16(xb + (size_t)p * 256 + qs * 8, &wa[idx * 8]);
    }
    #pragma unroll
    for (int it = 0; it < 12; ++it) {       // B: 96 rows x 32 chunks
        int idx = it * 256 + tid;
        int n = idx >> 5, q = idx & 31, qs = q ^ (n & 7);
        gll16(wq16 + (size_t)(o0 + n) * 256 + qs * 8, &wb[idx * 8]);
    }
    __syncthreads();

    const int lane = tid & 63;
    const int wid  = tid >> 6;
    const int m0   = wid * 16;
    const int ml   = lane & 15;
    const int kg   = lane >> 4;

    f32x4 acc[6];
    #pragma unroll
    for (int u = 0; u < 6; ++u) acc[u] = (f32x4){0.f, 0.f, 0.f, 0.f};

    #pragma unroll
    for (int ks = 0; ks < 8; ++ks) {
        const int pj = ((ks * 4 + kg) ^ (ml & 7)) * 8;   // swizzled chunk (m&7==n&7==ml&7)
        bf16x8 af = *(const bf16x8*)&wa[(m0 + ml) * 256 + pj];
        #pragma unroll
        for (int u = 0; u < 6; ++u) {
            bf16x8 bf = *(const bf16x8*)&wb[(u * 16 + ml) * 256 + pj];
            acc[u] = __builtin_amdgcn_mfma_f32_16x16x32_bf16(af, bf, acc[u], 0, 0, 0);
        }
    }

    #pragma unroll
    for (int u = 0; u < 6; ++u) {
        int o = o0 + u * 16 + ml;
        float bj = bias[o];
        uint2 st = { pk(acc[u][0] + bj, acc[u][1] + bj),
                     pk(acc[u][2] + bj, acc[u][3] + bj) };
        *(uint2*)(f16 + ((size_t)b * QKVC + o) * POS + p0 + m0 + kg * 4) = st;
    }
}

// ---------------------------------------------------------------------------
// attn v6: R4's proven two-pass body, bit-identical; staging rewritten:
//  - halo row padded to 60 words: col1 = left border, cols 2..57 = interior
//    (gx 0..55), col 58 = right border -> interior starts at EVEN col.
//  - interior loaded as coalesced u32 (2 bf16) from k/v planes: 2240 dword
//    tasks = exactly 5/thread, contiguous within each (ch, row-run)
//    -> 256 B per wave-instr (vs 128 B scalar u16 before, 21 instrs/thr).
//  - pack two k|(v<<16) words with 3 bit-ops, store ds_write_b64.
//  - borders pre-zeroed by 80 threads; only wave-uniform gy check remains.
// TBH=8, grid (7, 8, 16), 448 thr, LDS 19.2 KB.
// ---------------------------------------------------------------------------
#define TBH 8
#define HROW (TBH + 2)              // 10
#define HCOL 60                     // padded: [0]unused [1]L [2..57]int [58]R [59]unused
__global__ __launch_bounds__(448) void attn_kernel(const ushort_t* __restrict__ f16,
                                                   const float* __restrict__ wattn,
                                                   float* __restrict__ aout) {
    __shared__ __align__(16) unsigned int kvbuf[CH][HROW][HCOL];  // k | (v<<16)

    const int tid = threadIdx.x;
    const int ty0 = blockIdx.x * TBH;
    const int h   = blockIdx.y;
    const int b   = blockIdx.z;
    const ushort_t* fb = f16 + ((size_t)b * QKVC + h * 24) * POS;

    const int ly  = tid / WW;           // 0..7
    const int lx  = tid - ly * WW;
    const int pos = (ty0 + ly) * WW + lx;

    // q loads issued BEFORE staging: latency overlaps the stage loop
    float q[CH];
    #pragma unroll
    for (int ch = 0; ch < CH; ++ch) q[ch] = bu2f(fb[ch * POS + pos]) * SCALE;

    // zero L/R border columns (incl. corner rows)
    if (tid < 80) {
        int ch = tid / 10, row = tid - ch * 10;
        kvbuf[ch][row][1]  = 0;
        kvbuf[ch][row][58] = 0;
    }
    // interior: 8ch x 10row x 28 dword-pairs = 2240 tasks, 5 per thread
    #pragma unroll
    for (int it = 0; it < 5; ++it) {
        int idx  = it * 448 + tid;
        int ch   = idx / 280;
        int rem  = idx - ch * 280;
        int row  = rem / 28;
        int dcol = rem - row * 28;
        int gy   = ty0 + row - 1;
        unsigned int kk = 0, vv = 0;
        if (gy >= 0 && gy < HH) {           // wave-mostly-uniform row check
            int o = gy * WW + dcol * 2;
            kk = *(const unsigned int*)(fb + (8  + ch) * POS + o);
            vv = *(const unsigned int*)(fb + (16 + ch) * POS + o);
        }
        uint2 w;
        w.x = (kk & 0xffffu) | (vv << 16);
        w.y = (kk >> 16)     | (vv & 0xffff0000u);
        *(uint2*)&kvbuf[ch][row][2 + dcol * 2] = w;
    }
    __syncthreads();

    // per-(h,ch) fused weights: uniform -> s_load quads
    const float4* wh = (const float4*)wattn + (size_t)h * 8 * 27;

    // ---- pass 1: K-conv -> logits ----
    float logits[9];
    #pragma unroll
    for (int ka = 0; ka < 9; ++ka) logits[ka] = 0.f;
    #pragma unroll
    for (int ch = 0; ch < CH; ++ch) {
        float nk[9];
        #pragma unroll
        for (int dy = 0; dy < 3; ++dy)
            #pragma unroll
            for (int dx = 0; dx < 3; ++dx)
                nk[dy * 3 + dx] = lo2f(kvbuf[ch][ly + dy][lx + 1 + dx]);
        const float qc = q[ch];
        const float4* wp = wh + ch * 27;
        #pragma unroll
        for (int ka = 0; ka < 9; ++ka) {
            float4 a4 = wp[ka * 3 + 0];
            float4 b4 = wp[ka * 3 + 1];
            float4 c4 = wp[ka * 3 + 2];
            float kv = nk[ka] + c4.y;
            kv += nk[0]*a4.x + nk[1]*a4.y + nk[2]*a4.z + nk[3]*a4.w;
            kv += nk[4]*b4.x + nk[5]*b4.y + nk[6]*b4.z + nk[7]*b4.w;
            kv += nk[8]*c4.x;
            logits[ka] += qc * kv;
        }
    }

    // ---- softmax ----
    float m = logits[0];
    #pragma unroll
    for (int ka = 1; ka < 9; ++ka) m = fmaxf(m, logits[ka]);
    float att[9];
    float s = 0.f;
    #pragma unroll
    for (int ka = 0; ka < 9; ++ka) { att[ka] = __expf(logits[ka] - m); s += att[ka]; }
    float inv = 1.f / s;
    #pragma unroll
    for (int ka = 0; ka < 9; ++ka) att[ka] *= inv;

    // ---- pass 2: V-conv -> weighted sum, store per-ch (minimal live state) ----
    float* ap = aout + ((size_t)b * OC + h * CH) * POS + pos;
    #pragma unroll
    for (int ch = 0; ch < CH; ++ch) {
        float nv[9];
        #pragma unroll
        for (int dy = 0; dy < 3; ++dy)
            #pragma unroll
            for (int dx = 0; dx < 3; ++dx)
                nv[dy * 3 + dx] = hi2f(kvbuf[ch][ly + dy][lx + 1 + dx]);
        const float4* wp = wh + ch * 27;
        float o = 0.f;
        #pragma unroll
        for (int ka = 0; ka < 9; ++ka) {
            float4 a4 = wp[ka * 3 + 0];
            float4 b4 = wp[ka * 3 + 1];
            float4 c4 = wp[ka * 3 + 2];
            float vv = nv[ka] + c4.z;
            vv += nv[0]*a4.x + nv[1]*a4.y + nv[2]*a4.z + nv[3]*a4.w;
            vv += nv[4]*b4.x + nv[5]*b4.y + nv[6]*b4.z + nv[7]*b4.w;
            vv += nv[8]*c4.x;
            o += att[ka] * vv;
        }
        ap[ch * POS] = o;
    }
}
#undef TBH

// ---------------------------------------------------------------------------
// proj: out = a @ proj_w^T + b. A: coalesced fp32 -> LDS -> bf16 transpose.
// B: global_load_lds of pre-converted wp16 (swizzled). Mtile=64, Ntile=128.
// LDS ~42KB = 3 blk/CU. grid (49, 2, 16), 256 thr.
// ---------------------------------------------------------------------------
__global__ __launch_bounds__(256) void proj_mfma(const float* __restrict__ a,
                                                 const ushort_t* __restrict__ wp16,
                                                 const float* __restrict__ bias,
                                                 float* __restrict__ out) {
    __shared__ float ld[64][65];
    __shared__ __align__(16) ushort_t wa[64 * 72];
    __shared__ __align__(16) ushort_t wb[128 * 64];
    const int tid = threadIdx.x;
    const int p0 = blockIdx.x * 64, o0 = blockIdx.y * 128, b = blockIdx.z;

    // B: async GLL (rows 128B = 8 chunks, swizzled)
    #pragma unroll
    for (int it = 0; it < 4; ++it) {
        int idx = it * 256 + tid;
        int n = idx >> 3, q = idx & 7, qs = q ^ (n & 7);
        gll16(wp16 + (size_t)(o0 + n) * 64 + qs * 8, &wb[idx * 8]);
    }
    // A: coalesced fp32 tile
    const float* ab = a + (size_t)b * OC * POS + p0;
    #pragma unroll
    for (int it = 0; it < 4; ++it) {
        int idx = it * 256 + tid;
        int c = idx >> 4, pc = (idx & 15) << 2;
        float4 v = *(const float4*)(ab + (size_t)c * POS + pc);
        ld[c][pc] = v.x; ld[c][pc+1] = v.y; ld[c][pc+2] = v.z; ld[c][pc+3] = v.w;
    }
    __syncthreads();
    // pack transpose: wa[p][ch] stride 72
    #pragma unroll
    for (int it = 0; it < 2; ++it) {
        int idx = it * 256 + tid;
        int p = idx >> 3, q = (idx & 7) * 8;
        uint4 st = { pk(ld[q][p],   ld[q+1][p]), pk(ld[q+2][p], ld[q+3][p]),
                     pk(ld[q+4][p], ld[q+5][p]), pk(ld[q+6][p], ld[q+7][p]) };
        *(uint4*)&wa[p * 72 + q] = st;
    }
    __syncthreads();

    const int lane = tid & 63;
    const int wid  = tid >> 6;
    const int m0   = wid * 16;
    const int ml   = lane & 15;
    const int kg   = lane >> 4;

    f32x4 acc[8];
    #pragma unroll
    for (int u = 0; u < 8; ++u) acc[u] = (f32x4){0.f, 0.f, 0.f, 0.f};

    #pragma unroll
    for (int s = 0; s < 2; ++s) {
        bf16x8 af = *(const bf16x8*)&wa[(m0 + ml) * 72 + s * 32 + kg * 8];
        const int pj = ((s * 4 + kg) ^ (ml & 7)) * 8;
        #pragma unroll
        for (int u = 0; u < 8; ++u) {
            bf16x8 bf = *(const bf16x8*)&wb[(u * 16 + ml) * 64 + pj];
            acc[u] = __builtin_amdgcn_mfma_f32_16x16x32_bf16(af, bf, acc[u], 0, 0, 0);
        }
    }

    #pragma unroll
    for (int u = 0; u < 8; ++u) {
        int o = o0 + u * 16 + ml;
        float bj = bias[o];
        float4 st = { acc[u][0] + bj, acc[u][1] + bj, acc[u][2] + bj, acc[u][3] + bj };
        *(float4*)(out + ((size_t)b * 256 + o) * POS + p0 + m0 + kg * 4) = st;
    }
}

// ---------------------------------------------------------------------------
extern "C" void kernel_launch(void* const* d_in, const int* in_sizes, int n_in,
                              void* d_out, int out_size, void* d_ws, size_t ws_size,
                              hipStream_t stream) {
    const float* x      = (const float*)d_in[0];
    const float* qkv_w  = (const float*)d_in[1];
    const float* qkv_b  = (const float*)d_in[2];
    const float* dc_b   = (const float*)d_in[3];
    const float* dc1_w  = (const float*)d_in[4];
    const float* dc1_b  = (const float*)d_in[5];
    const float* rpb    = (const float*)d_in[6];
    const float* proj_w = (const float*)d_in[7];
    const float* proj_b = (const float*)d_in[8];
    float* out = (float*)d_out;

    // ws layout (45.1 MB base):
    //   f16   bf16 16*192*3136 = 19.27 MB
    //   xT    bf16 16*3136*256 = 25.69 MB  (dead after qkv; 'a' aliases it)
    //   wq16  96 KB, wp16 32 KB
    //   wattn 27 KB (fused attn weights) -- falls back to d_out scratch if
    //   ws is exactly-sized (d_out fully overwritten by proj afterwards).
    ushort_t* f16  = (ushort_t*)d_ws;
    ushort_t* xT   = f16 + (size_t)BATCH * QKVC * POS;
    ushort_t* wq16 = xT + (size_t)BATCH * POS * 256;
    ushort_t* wp16 = wq16 + 192 * 256;
    float*    a    = (float*)xT;            // alias: xT dead before attn writes

    const size_t WS_BASE = 45088768;        // bytes used by the four bufs above
    float* wattn = (ws_size >= WS_BASE + 6912 * sizeof(float))
                 ? (float*)((char*)d_ws + WS_BASE)
                 : (float*)d_out;           // scratch; proj rewrites all of out

    prep_xw  <<<dim3(49, 4, BATCH + 1), 256, 0, stream>>>(x, xT, qkv_w, proj_w,
                                                          dc_b, dc1_w, dc1_b, rpb,
                                                          wq16, wp16, wattn);
    qkv_mfma <<<dim3(49, 2, BATCH), 256, 0, stream>>>(xT, wq16, qkv_b, f16);
    attn_kernel<<<dim3(7, NH, BATCH), 448, 0, stream>>>(f16, wattn, a);
    proj_mfma<<<dim3(49, 2, BATCH), 256, 0, stream>>>(a, wp16, proj_b, out);
}

// Round 6
// 180.113 us; speedup vs baseline: 1.2238x; 1.0258x over previous
//
#include <hip/hip_runtime.h>
#include <hip/hip_bf16.h>

#define BATCH 16
#define NH    8
#define CH    8
#define HH    56
#define WW    56
#define POS   3136          // 56*56 = 49*64
#define QKVC  192
#define OC    64
#define SCALE 0.17677669529663687f   // 32^-0.5

typedef unsigned short ushort_t;
typedef __attribute__((ext_vector_type(8))) short bf16x8;   // 8 bf16 = 4 VGPRs
typedef __attribute__((ext_vector_type(4))) float f32x4;

__device__ __forceinline__ unsigned short f2b(float f) {
    __hip_bfloat16 h = __float2bfloat16(f);
    union { __hip_bfloat16 h; unsigned short u; } c; c.h = h; return c.u;
}
__device__ __forceinline__ unsigned int pk(float lo, float hi) {
    return (unsigned int)f2b(lo) | ((unsigned int)f2b(hi) << 16);
}
__device__ __forceinline__ float bu2f(ushort_t u) {
    union { unsigned int v; float f; } c; c.v = ((unsigned int)u) << 16; return c.f;
}
__device__ __forceinline__ float lo2f(unsigned int w) {       // low bf16 -> f32
    union { unsigned int v; float f; } c; c.v = w << 16; return c.f;
}
__device__ __forceinline__ float hi2f(unsigned int w) {       // high bf16 -> f32
    union { unsigned int v; float f; } c; c.v = w & 0xffff0000u; return c.f;
}
// async 16B global->LDS (lane-linear dest within wave)
__device__ __forceinline__ void gll16(const ushort_t* g, ushort_t* l) {
    __builtin_amdgcn_global_load_lds((const __attribute__((address_space(1))) void*)g,
                                     (__attribute__((address_space(3))) void*)l, 16, 0, 0);
}

// ---------------------------------------------------------------------------
// prep_w: qkv_w (192x256) + proj_w (256x64) fp32 -> bf16, PLUS fused attn
// weight tensor wattn[h][ch][ka][12] = {w0..w8, db+rpb, db, 0}.
// grid(67), 256 thr. Tiny (~4 us). prep_x is GONE: its transpose is fused
// into qkv_mfma, eliminating the 25.7MB xT write + 2x25.7MB reads.
// ---------------------------------------------------------------------------
__global__ __launch_bounds__(256) void prep_w(const float* __restrict__ wq,
                                              const float* __restrict__ wp,
                                              const float* __restrict__ dc_b,
                                              const float* __restrict__ dc1_w,
                                              const float* __restrict__ dc1_b,
                                              const float* __restrict__ rpb,
                                              ushort_t* __restrict__ wq16,
                                              ushort_t* __restrict__ wp16,
                                              float* __restrict__ wattn) {
    int idx = blockIdx.x * 256 + threadIdx.x;   // 16384 float4 units + wattn slots
    if (idx >= 16384) {
        int t = idx - 16384;                    // need 576 = 8h * 72(ch*9+ka)
        if (t < 576) {
            int h = t / 72, r = t - h * 72;     // r = ch*9 + ka
            int ka = r % 9;
            float db = dc_b[r] + dc1_b[r];
            float* w = wattn + t * 12;          // t == (h*8+ch)*9 + ka
            #pragma unroll
            for (int j = 0; j < 9; ++j) w[j] = dc1_w[r * 9 + j];
            w[9]  = db + rpb[h * 9 + ka];       // K-branch bias (incl. rpb)
            w[10] = db;                         // V-branch bias
            w[11] = 0.f;
        }
        return;
    }
    const float* src; ushort_t* dst; int off;
    if (idx < 12288) { src = wq; dst = wq16; off = idx * 4; }
    else             { src = wp; dst = wp16; off = (idx - 12288) * 4; }
    float4 v = *(const float4*)(src + off);
    uint2 st = { pk(v.x, v.y), pk(v.z, v.w) };
    *(uint2*)(dst + off) = st;
}

// ---------------------------------------------------------------------------
// qkv v2 (fused transpose): f = x @ qkv_w^T + b via bf16 MFMA, f bf16
// [b][o][pos]. A is built DIRECTLY from x fp32: wave w, lane p loads 8
// ch-strided scalars per octet q (each instr = 64 consecutive p -> 256B
// coalesced), converts to bf16, ds_write_b128 at the same XOR-swizzled
// chunk the old gll16 path produced (LDS[q^(p&7)]=src[q] == LDS[q]=
// src[q^(p&7)], XOR involution; banks covered exactly once per 8 lanes).
// N=192 handled INSIDE the block (compute half 0 -> restage wb -> half 1)
// so x is read exactly once (51.4 MB total). Mtile=64, full K=256.
// LDS 80KB = 2 blk/CU. grid (49, 1, 16), 256 thr.
// ---------------------------------------------------------------------------
__global__ __launch_bounds__(256) void qkv_mfma(const float* __restrict__ x,
                                                const ushort_t* __restrict__ wq16,
                                                const float* __restrict__ bias,
                                                ushort_t* __restrict__ f16) {
    __shared__ __align__(16) ushort_t wa[64 * 256];
    __shared__ __align__(16) ushort_t wb[96 * 256];
    const int tid = threadIdx.x;
    const int p0 = blockIdx.x * 64, b = blockIdx.z;

    // B half 0: async GLL (rows 512B, chunk q stored at q^(n&7))
    #pragma unroll
    for (int it = 0; it < 12; ++it) {
        int idx = it * 256 + tid;
        int n = idx >> 5, q = idx & 31, qs = q ^ (n & 7);
        gll16(wq16 + (size_t)n * 256 + qs * 8, &wb[idx * 8]);
    }

    // A: fused transpose from x fp32 (overlaps the async B loads)
    const int p = tid & 63;             // pos within tile
    const int w = tid >> 6;             // wave id 0..3
    {
        const float* xp = x + (size_t)b * 256 * POS + p0 + p;
        #pragma unroll
        for (int it = 0; it < 8; ++it) {
            int q = it * 4 + w;         // ch-octet 0..31
            const float* xc = xp + (size_t)q * 8 * POS;
            uint4 st = { pk(xc[0],       xc[POS]),
                         pk(xc[2 * POS], xc[3 * POS]),
                         pk(xc[4 * POS], xc[5 * POS]),
                         pk(xc[6 * POS], xc[7 * POS]) };
            *(uint4*)&wa[p * 256 + ((q ^ (p & 7)) * 8)] = st;
        }
    }
    __syncthreads();

    const int lane = tid & 63;
    const int wid  = tid >> 6;
    const int m0   = wid * 16;
    const int ml   = lane & 15;
    const int kg   = lane >> 4;

    #pragma unroll
    for (int half = 0; half < 2; ++half) {
        f32x4 acc[6];
        #pragma unroll
        for (int u = 0; u < 6; ++u) acc[u] = (f32x4){0.f, 0.f, 0.f, 0.f};

        #pragma unroll
        for (int ks = 0; ks < 8; ++ks) {
            const int pj = ((ks * 4 + kg) ^ (ml & 7)) * 8;   // swizzled chunk
            bf16x8 af = *(const bf16x8*)&wa[(m0 + ml) * 256 + pj];
            #pragma unroll
            for (int u = 0; u < 6; ++u) {
                bf16x8 bf = *(const bf16x8*)&wb[(u * 16 + ml) * 256 + pj];
                acc[u] = __builtin_amdgcn_mfma_f32_16x16x32_bf16(af, bf, acc[u], 0, 0, 0);
            }
        }

        #pragma unroll
        for (int u = 0; u < 6; ++u) {
            int o = half * 96 + u * 16 + ml;
            float bj = bias[o];
            uint2 st = { pk(acc[u][0] + bj, acc[u][1] + bj),
                         pk(acc[u][2] + bj, acc[u][3] + bj) };
            *(uint2*)(f16 + ((size_t)b * QKVC + o) * POS + p0 + m0 + kg * 4) = st;
        }

        if (half == 0) {
            __syncthreads();            // all wb reads of half 0 complete
            #pragma unroll
            for (int it = 0; it < 12; ++it) {
                int idx = it * 256 + tid;
                int n = idx >> 5, q = idx & 31, qs = q ^ (n & 7);
                gll16(wq16 + (size_t)(96 + n) * 256 + qs * 8, &wb[idx * 8]);
            }
            __syncthreads();
        }
    }
}

// ---------------------------------------------------------------------------
// attn v6 (unchanged from R5): two-pass body, bit-packed k|(v<<16) LDS,
// padded halo rows (interior at even cols), coalesced u32 staging.
// TBH=8, grid (7, 8, 16), 448 thr, LDS 19.2 KB.
// ---------------------------------------------------------------------------
#define TBH 8
#define HROW (TBH + 2)              // 10
#define HCOL 60                     // padded: [0]unused [1]L [2..57]int [58]R [59]unused
__global__ __launch_bounds__(448) void attn_kernel(const ushort_t* __restrict__ f16,
                                                   const float* __restrict__ wattn,
                                                   float* __restrict__ aout) {
    __shared__ __align__(16) unsigned int kvbuf[CH][HROW][HCOL];  // k | (v<<16)

    const int tid = threadIdx.x;
    const int ty0 = blockIdx.x * TBH;
    const int h   = blockIdx.y;
    const int b   = blockIdx.z;
    const ushort_t* fb = f16 + ((size_t)b * QKVC + h * 24) * POS;

    const int ly  = tid / WW;           // 0..7
    const int lx  = tid - ly * WW;
    const int pos = (ty0 + ly) * WW + lx;

    // q loads issued BEFORE staging: latency overlaps the stage loop
    float q[CH];
    #pragma unroll
    for (int ch = 0; ch < CH; ++ch) q[ch] = bu2f(fb[ch * POS + pos]) * SCALE;

    // zero L/R border columns (incl. corner rows)
    if (tid < 80) {
        int ch = tid / 10, row = tid - ch * 10;
        kvbuf[ch][row][1]  = 0;
        kvbuf[ch][row][58] = 0;
    }
    // interior: 8ch x 10row x 28 dword-pairs = 2240 tasks, 5 per thread
    #pragma unroll
    for (int it = 0; it < 5; ++it) {
        int idx  = it * 448 + tid;
        int ch   = idx / 280;
        int rem  = idx - ch * 280;
        int row  = rem / 28;
        int dcol = rem - row * 28;
        int gy   = ty0 + row - 1;
        unsigned int kk = 0, vv = 0;
        if (gy >= 0 && gy < HH) {           // wave-mostly-uniform row check
            int o = gy * WW + dcol * 2;
            kk = *(const unsigned int*)(fb + (8  + ch) * POS + o);
            vv = *(const unsigned int*)(fb + (16 + ch) * POS + o);
        }
        uint2 w;
        w.x = (kk & 0xffffu) | (vv << 16);
        w.y = (kk >> 16)     | (vv & 0xffff0000u);
        *(uint2*)&kvbuf[ch][row][2 + dcol * 2] = w;
    }
    __syncthreads();

    // per-(h,ch) fused weights: uniform -> s_load quads
    const float4* wh = (const float4*)wattn + (size_t)h * 8 * 27;

    // ---- pass 1: K-conv -> logits ----
    float logits[9];
    #pragma unroll
    for (int ka = 0; ka < 9; ++ka) logits[ka] = 0.f;
    #pragma unroll
    for (int ch = 0; ch < CH; ++ch) {
        float nk[9];
        #pragma unroll
        for (int dy = 0; dy < 3; ++dy)
            #pragma unroll
            for (int dx = 0; dx < 3; ++dx)
                nk[dy * 3 + dx] = lo2f(kvbuf[ch][ly + dy][lx + 1 + dx]);
        const float qc = q[ch];
        const float4* wp = wh + ch * 27;
        #pragma unroll
        for (int ka = 0; ka < 9; ++ka) {
            float4 a4 = wp[ka * 3 + 0];
            float4 b4 = wp[ka * 3 + 1];
            float4 c4 = wp[ka * 3 + 2];
            float kv = nk[ka] + c4.y;
            kv += nk[0]*a4.x + nk[1]*a4.y + nk[2]*a4.z + nk[3]*a4.w;
            kv += nk[4]*b4.x + nk[5]*b4.y + nk[6]*b4.z + nk[7]*b4.w;
            kv += nk[8]*c4.x;
            logits[ka] += qc * kv;
        }
    }

    // ---- softmax ----
    float m = logits[0];
    #pragma unroll
    for (int ka = 1; ka < 9; ++ka) m = fmaxf(m, logits[ka]);
    float att[9];
    float s = 0.f;
    #pragma unroll
    for (int ka = 0; ka < 9; ++ka) { att[ka] = __expf(logits[ka] - m); s += att[ka]; }
    float inv = 1.f / s;
    #pragma unroll
    for (int ka = 0; ka < 9; ++ka) att[ka] *= inv;

    // ---- pass 2: V-conv -> weighted sum, store per-ch (minimal live state) ----
    float* ap = aout + ((size_t)b * OC + h * CH) * POS + pos;
    #pragma unroll
    for (int ch = 0; ch < CH; ++ch) {
        float nv[9];
        #pragma unroll
        for (int dy = 0; dy < 3; ++dy)
            #pragma unroll
            for (int dx = 0; dx < 3; ++dx)
                nv[dy * 3 + dx] = hi2f(kvbuf[ch][ly + dy][lx + 1 + dx]);
        const float4* wp = wh + ch * 27;
        float o = 0.f;
        #pragma unroll
        for (int ka = 0; ka < 9; ++ka) {
            float4 a4 = wp[ka * 3 + 0];
            float4 b4 = wp[ka * 3 + 1];
            float4 c4 = wp[ka * 3 + 2];
            float vv = nv[ka] + c4.z;
            vv += nv[0]*a4.x + nv[1]*a4.y + nv[2]*a4.z + nv[3]*a4.w;
            vv += nv[4]*b4.x + nv[5]*b4.y + nv[6]*b4.z + nv[7]*b4.w;
            vv += nv[8]*c4.x;
            o += att[ka] * vv;
        }
        ap[ch * POS] = o;
    }
}
#undef TBH

// ---------------------------------------------------------------------------
// proj (unchanged): out = a @ proj_w^T + b. Mtile=64, Ntile=128.
// LDS ~42KB = 3 blk/CU. grid (49, 2, 16), 256 thr.
// ---------------------------------------------------------------------------
__global__ __launch_bounds__(256) void proj_mfma(const float* __restrict__ a,
                                                 const ushort_t* __restrict__ wp16,
                                                 const float* __restrict__ bias,
                                                 float* __restrict__ out) {
    __shared__ float ld[64][65];
    __shared__ __align__(16) ushort_t wa[64 * 72];
    __shared__ __align__(16) ushort_t wb[128 * 64];
    const int tid = threadIdx.x;
    const int p0 = blockIdx.x * 64, o0 = blockIdx.y * 128, b = blockIdx.z;

    // B: async GLL (rows 128B = 8 chunks, swizzled)
    #pragma unroll
    for (int it = 0; it < 4; ++it) {
        int idx = it * 256 + tid;
        int n = idx >> 3, q = idx & 7, qs = q ^ (n & 7);
        gll16(wp16 + (size_t)(o0 + n) * 64 + qs * 8, &wb[idx * 8]);
    }
    // A: coalesced fp32 tile
    const float* ab = a + (size_t)b * OC * POS + p0;
    #pragma unroll
    for (int it = 0; it < 4; ++it) {
        int idx = it * 256 + tid;
        int c = idx >> 4, pc = (idx & 15) << 2;
        float4 v = *(const float4*)(ab + (size_t)c * POS + pc);
        ld[c][pc] = v.x; ld[c][pc+1] = v.y; ld[c][pc+2] = v.z; ld[c][pc+3] = v.w;
    }
    __syncthreads();
    // pack transpose: wa[p][ch] stride 72
    #pragma unroll
    for (int it = 0; it < 2; ++it) {
        int idx = it * 256 + tid;
        int p = idx >> 3, q = (idx & 7) * 8;
        uint4 st = { pk(ld[q][p],   ld[q+1][p]), pk(ld[q+2][p], ld[q+3][p]),
                     pk(ld[q+4][p], ld[q+5][p]), pk(ld[q+6][p], ld[q+7][p]) };
        *(uint4*)&wa[p * 72 + q] = st;
    }
    __syncthreads();

    const int lane = tid & 63;
    const int wid  = tid >> 6;
    const int m0   = wid * 16;
    const int ml   = lane & 15;
    const int kg   = lane >> 4;

    f32x4 acc[8];
    #pragma unroll
    for (int u = 0; u < 8; ++u) acc[u] = (f32x4){0.f, 0.f, 0.f, 0.f};

    #pragma unroll
    for (int s = 0; s < 2; ++s) {
        bf16x8 af = *(const bf16x8*)&wa[(m0 + ml) * 72 + s * 32 + kg * 8];
        const int pj = ((s * 4 + kg) ^ (ml & 7)) * 8;
        #pragma unroll
        for (int u = 0; u < 8; ++u) {
            bf16x8 bf = *(const bf16x8*)&wb[(u * 16 + ml) * 64 + pj];
            acc[u] = __builtin_amdgcn_mfma_f32_16x16x32_bf16(af, bf, acc[u], 0, 0, 0);
        }
    }

    #pragma unroll
    for (int u = 0; u < 8; ++u) {
        int o = o0 + u * 16 + ml;
        float bj = bias[o];
        float4 st = { acc[u][0] + bj, acc[u][1] + bj, acc[u][2] + bj, acc[u][3] + bj };
        *(float4*)(out + ((size_t)b * 256 + o) * POS + p0 + m0 + kg * 4) = st;
    }
}

// ---------------------------------------------------------------------------
extern "C" void kernel_launch(void* const* d_in, const int* in_sizes, int n_in,
                              void* d_out, int out_size, void* d_ws, size_t ws_size,
                              hipStream_t stream) {
    const float* x      = (const float*)d_in[0];
    const float* qkv_w  = (const float*)d_in[1];
    const float* qkv_b  = (const float*)d_in[2];
    const float* dc_b   = (const float*)d_in[3];
    const float* dc1_w  = (const float*)d_in[4];
    const float* dc1_b  = (const float*)d_in[5];
    const float* rpb    = (const float*)d_in[6];
    const float* proj_w = (const float*)d_in[7];
    const float* proj_b = (const float*)d_in[8];
    float* out = (float*)d_out;

    // ws layout (32.27 MB base — xT is GONE, transpose fused into qkv):
    //   f16   bf16 16*192*3136 = 19.27 MB
    //   a     fp32 16*64*3136  = 12.85 MB
    //   wq16  96 KB, wp16 32 KB
    //   wattn 27 KB (fused attn weights) -- d_out fallback if ws exact.
    ushort_t* f16  = (ushort_t*)d_ws;
    float*    a    = (float*)(f16 + (size_t)BATCH * QKVC * POS);
    ushort_t* wq16 = (ushort_t*)(a + (size_t)BATCH * OC * POS);
    ushort_t* wp16 = wq16 + 192 * 256;

    const size_t WS_BASE = 32243712;        // bytes used by the four bufs above
    float* wattn = (ws_size >= WS_BASE + 6912 * sizeof(float))
                 ? (float*)((char*)d_ws + WS_BASE)
                 : (float*)d_out;           // scratch; proj rewrites all of out

    prep_w   <<<dim3(67),           256, 0, stream>>>(qkv_w, proj_w, dc_b, dc1_w,
                                                      dc1_b, rpb, wq16, wp16, wattn);
    qkv_mfma <<<dim3(49, 1, BATCH), 256, 0, stream>>>(x, wq16, qkv_b, f16);
    attn_kernel<<<dim3(7, NH, BATCH), 448, 0, stream>>>(f16, wattn, a);
    proj_mfma<<<dim3(49, 2, BATCH), 256, 0, stream>>>(a, wp16, proj_b, out);
}